// Round 5
// baseline (509.875 us; speedup 1.0000x reference)
//
#include <hip/hip_runtime.h>

// JetMoE FFN: B=2,S=2048 -> T=4096 tokens, D=1024, E=8, F=2048, top_k=2.
// Sparse (top-2) expert-bucketed grouped GEMM in bf16 MFMA, fp32 accum.
// R5: occupancy attack. 512-thread GEMM blocks, per-wave tile M64xN32
//     (64 AGPR for g+v in gemm1, 32 in gemm2) -> 3 blocks/CU gemm1,
//     4 blocks/CU gemm2 (vs 2 before; R4 showed Occupancy 15.6%, all pipes
//     <30% = latency-bound). gemm2 adds split-K=2 (halves barriers/block,
//     doubles blocks; out is accumulated atomically anyway).
// ws layout (~148 MB): see offsets in kernel_launch.

#define T_TOK 4096
#define DIM   1024
#define NEXP  8
#define FF    2048
#define YB    16
#define BK    64

typedef __attribute__((ext_vector_type(8))) short short8;
typedef __attribute__((ext_vector_type(4))) float f32x4;

__device__ __forceinline__ unsigned short f2b(float f) {
  unsigned int u = __builtin_bit_cast(unsigned int, f);
  u += 0x7fffu + ((u >> 16) & 1u);   // round-to-nearest-even
  return (unsigned short)(u >> 16);
}

// async global->LDS, 16B per lane; lds dest = wave-uniform base + lane*16
__device__ __forceinline__ void gll16(const unsigned short* g, unsigned short* l) {
  __builtin_amdgcn_global_load_lds(
      (const __attribute__((address_space(1))) unsigned int*)g,
      (__attribute__((address_space(3))) unsigned int*)l, 16, 0, 0);
}

// Stage a 128xBK bf16 tile from 8 waves (512 threads), row-rotated chunk
// swizzle: logical 16B-chunk c of row r -> physical chunk (c+r)&7. LDS dest
// stays base+lane*16 (gll16 contiguity rule); rotation folded into the
// per-lane GLOBAL source address.
__device__ __forceinline__ void stage8(const unsigned short* __restrict__ gbase,
                                       size_t ldk, int k0,
                                       unsigned short* __restrict__ lds,
                                       int w, int lane) {
#pragma unroll
  for (int i = 0; i < 2; i++) {
    const int s = w * 128 + i * 64 + lane;   // physical slot, 16B units
    const int r = s >> 3;
    const int pc = s & 7;
    const int gc = ((pc - r) & 7) * 8;
    gll16(gbase + (size_t)r * ldk + k0 + gc, lds + (size_t)s * 8);
  }
}

// read MFMA fragment (8 bf16, k-contiguous) honoring the rotation swizzle
__device__ __forceinline__ short8 frag_read(const unsigned short* __restrict__ lds,
                                            int row, int kk, int quad) {
  const int p = ((kk * 4 + quad) + row) & 7;
  return __builtin_bit_cast(short8, *(const uint4*)(lds + (size_t)row * BK + p * 8));
}

// ---------------- router: fp64 logits/top-k, NO global atomics -------------
__global__ void router_k(const float* __restrict__ x, const float* __restrict__ rw,
                         int* __restrict__ tok_e, float* __restrict__ tok_g,
                         float* __restrict__ psum_part) {
  const int t = blockIdx.x * 4 + (threadIdx.x >> 6);  // one wave per token
  const int lane = threadIdx.x & 63;
  double acc[8];
#pragma unroll
  for (int e = 0; e < 8; e++) acc[e] = 0.0;
  const float* xr = x + (size_t)t * DIM;
#pragma unroll
  for (int d0 = 0; d0 < DIM; d0 += 256) {
    const int d = d0 + lane * 4;
    float4 xv = *(const float4*)(xr + d);
    const float* rwr = rw + d * 8;
#pragma unroll
    for (int j = 0; j < 4; j++) {
      double xd = (double)((j == 0) ? xv.x : (j == 1) ? xv.y : (j == 2) ? xv.z : xv.w);
#pragma unroll
      for (int e = 0; e < 8; e++) acc[e] += xd * (double)rwr[j * 8 + e];
    }
  }
#pragma unroll
  for (int off = 32; off > 0; off >>= 1) {
#pragma unroll
    for (int e = 0; e < 8; e++) acc[e] += __shfl_down(acc[e], off, 64);
  }
  __shared__ float pblk[8];
  if (threadIdx.x < 8) pblk[threadIdx.x] = 0.f;
  __syncthreads();
  if (lane == 0) {
    int i0 = -1, i1 = -1;
    double v0 = -1e300, v1 = -1e300;
#pragma unroll
    for (int e = 0; e < 8; e++) {
      double v = acc[e];
      if (v > v0) { v1 = v0; i1 = i0; v0 = v; i0 = e; }
      else if (v > v1) { v1 = v; i1 = e; }
    }
    float g1 = 1.f / (1.f + __expf((float)(v0 - v1)));  // gate of 2nd expert
    tok_e[t * 2] = i0; tok_e[t * 2 + 1] = i1;
    tok_g[t * 2] = 1.f - g1; tok_g[t * 2 + 1] = g1;
    float s = 0.f; float p[8];
#pragma unroll
    for (int e = 0; e < 8; e++) { p[e] = __expf((float)(acc[e] - v0)); s += p[e]; }
    float inv = 1.f / s;
#pragma unroll
    for (int e = 0; e < 8; e++) atomicAdd(&pblk[e], p[e] * inv);  // LDS only
  }
  __syncthreads();
  if (threadIdx.x < 8) psum_part[blockIdx.x * 8 + threadIdx.x] = pblk[threadIdx.x];
}

// ---------------- bucket: slots via ballot + LDS atomics, aux loss ---------
__global__ __launch_bounds__(1024) void bucket_k(
    const int* __restrict__ tok_e, const float* __restrict__ tok_g,
    const float* __restrict__ psum_part,
    int* __restrict__ cnt, int* __restrict__ off,
    int* __restrict__ slot_t, float* __restrict__ slot_g,
    float* __restrict__ out_aux) {
  const int tid = threadIdx.x;
  const int lane = tid & 63;
  __shared__ int lcnt[8];
  __shared__ float fsum[8];
  if (tid < 8) { lcnt[tid] = 0; fsum[tid] = 0.f; }
  __syncthreads();
#pragma unroll
  for (int rep = 0; rep < 4; rep++) {
    const int t = rep * 1024 + tid;
    const int e0 = tok_e[t * 2], e1 = tok_e[t * 2 + 1];
    const float g0 = tok_g[t * 2], g1 = tok_g[t * 2 + 1];
#pragma unroll
    for (int which = 0; which < 2; which++) {
      const int e = which ? e1 : e0;
      const float g = which ? g1 : g0;
      int slot = 0;
#pragma unroll
      for (int ex = 0; ex < 8; ex++) {
        unsigned long long m = __ballot(e == ex);
        int base = 0;
        int first = __ffsll((long long)m) - 1;
        if (m != 0ull && lane == first) base = atomicAdd(&lcnt[ex], __popcll(m));
        base = __shfl(base, first & 63, 64);
        if (e == ex) slot = base + __popcll(m & ((1ull << lane) - 1ull));
      }
      slot_t[e * T_TOK + slot] = t;
      slot_g[e * T_TOK + slot] = g;
    }
  }
  float p[8];
#pragma unroll
  for (int e = 0; e < 8; e++) p[e] = psum_part[tid * 8 + e];
#pragma unroll
  for (int o = 32; o > 0; o >>= 1) {
#pragma unroll
    for (int e = 0; e < 8; e++) p[e] += __shfl_down(p[e], o, 64);
  }
  if (lane == 0) {
#pragma unroll
    for (int e = 0; e < 8; e++) atomicAdd(&fsum[e], p[e]);
  }
  __syncthreads();
  if (tid == 0) {
    int o = 0; float aux = 0.f;
    for (int e = 0; e < 8; e++) {
      cnt[e] = lcnt[e]; off[e] = o; o += lcnt[e];
      aux += ((float)lcnt[e] / (4096.f * 2.f)) * (fsum[e] / 4096.f);
    }
    out_aux[0] = 8.f * aux;
  }
}

// ---------------- init out = bias ------------------------------------------
__global__ void init_out_k(float* __restrict__ out, const float* __restrict__ bias) {
  int i = blockIdx.x * 256 + threadIdx.x;
  out[i] = bias[i & (DIM - 1)];
}

// ---------------- transpose fp32 [E][K][N] -> bf16 [E][N][K] ---------------
__global__ void transpose_k(const float* __restrict__ src, unsigned short* __restrict__ dst,
                            int K, int N) {
  __shared__ float tile[64][65];
  const int e = blockIdx.z;
  const int kb = blockIdx.y * 64, nb = blockIdx.x * 64;
  const float* s = src + (size_t)e * K * N;
  unsigned short* d = dst + (size_t)e * N * K;
  const int tid = threadIdx.x;
  const int r = tid >> 2;
  const int cseg = (tid & 3) * 16;
#pragma unroll
  for (int j = 0; j < 16; j += 4) {
    float4 v = *(const float4*)(s + (size_t)(kb + r) * N + nb + cseg + j);
    tile[r][cseg + j] = v.x; tile[r][cseg + j + 1] = v.y;
    tile[r][cseg + j + 2] = v.z; tile[r][cseg + j + 3] = v.w;
  }
  __syncthreads();
#pragma unroll
  for (int j = 0; j < 16; j += 4) {
    ushort4 o4;
    o4.x = f2b(tile[cseg + j][r]);
    o4.y = f2b(tile[cseg + j + 1][r]);
    o4.z = f2b(tile[cseg + j + 2][r]);
    o4.w = f2b(tile[cseg + j + 3][r]);
    *(ushort4*)(d + (size_t)(nb + r) * K + kb + cseg + j) = o4;
  }
}

// ---------------- gather tokens -> compact bf16 A ---------------------------
__global__ void gather_k(const float* __restrict__ x, const int* __restrict__ cnt,
                         const int* __restrict__ off, const int* __restrict__ slot_t,
                         unsigned short* __restrict__ A1) {
  const int e = blockIdx.z;
  const int rb = blockIdx.y * 128;
  const int c = cnt[e];
  if (rb >= c) return;
  const int o = off[e];
  const int cb = blockIdx.x * 128;                 // 8 column blocks of 128
  for (int i = threadIdx.x; i < 128 * 32; i += 256) {  // unit = float4
    int r = i >> 5;
    int seg = cb + (i & 31) * 4;
    int row = rb + r;
    if (row >= c) continue;
    int t = slot_t[e * T_TOK + row];
    float4 v = *(const float4*)(x + (size_t)t * DIM + seg);
    ushort4 o4;
    o4.x = f2b(v.x); o4.y = f2b(v.y); o4.z = f2b(v.z); o4.w = f2b(v.w);
    *(ushort4*)(A1 + (size_t)(o + row) * DIM + seg) = o4;
  }
}

// ---------------- GEMM1: A[rows,1024] x W1T -> GLU -> H bf16 ---------------
// 512 threads, 8 waves; wave tile M64 x N32 (g and v) -> 64 AGPR/wave.
__global__ __launch_bounds__(512, 3) void gemm1_k(
    const unsigned short* __restrict__ A1, const unsigned short* __restrict__ W1T,
    unsigned short* __restrict__ H, const int* __restrict__ cnt, const int* __restrict__ off) {
  const int e = blockIdx.z;
  const int c = cnt[e];
  const int rb = blockIdx.y * 128;
  if (rb >= c) return;
  const int o = off[e];
  const unsigned short* Ab = A1 + (size_t)(o + rb) * DIM;
  const unsigned short* Bgb = W1T + ((size_t)e * 4096 + blockIdx.x * 128) * DIM;
  const unsigned short* Bvb = Bgb + (size_t)2048 * DIM;

  __shared__ __align__(16) unsigned short As[128][BK];
  __shared__ __align__(16) unsigned short Bg[128][BK];
  __shared__ __align__(16) unsigned short Bv[128][BK];

  const int tid = threadIdx.x;
  const int lane = tid & 63;
  const int w = tid >> 6;            // 0..7
  const int mq = (w & 1) * 64;       // 2 m-groups
  const int nq = (w >> 1) * 32;      // 4 n-groups
  const int fr = lane & 15;
  const int quad = lane >> 4;

  f32x4 accg[4][2], accv[4][2];
  const f32x4 zero = {0.f, 0.f, 0.f, 0.f};
#pragma unroll
  for (int i = 0; i < 4; i++)
#pragma unroll
    for (int j = 0; j < 2; j++) { accg[i][j] = zero; accv[i][j] = zero; }

  for (int k0 = 0; k0 < DIM; k0 += BK) {
    stage8(Ab,  DIM, k0, &As[0][0], w, lane);
    stage8(Bgb, DIM, k0, &Bg[0][0], w, lane);
    stage8(Bvb, DIM, k0, &Bv[0][0], w, lane);
    __syncthreads();

#pragma unroll
    for (int kk = 0; kk < 2; kk++) {
      short8 af[4], bgf[2], bvf[2];
#pragma unroll
      for (int mi = 0; mi < 4; mi++)
        af[mi] = frag_read(&As[0][0], mq + mi * 16 + fr, kk, quad);
#pragma unroll
      for (int ni = 0; ni < 2; ni++) {
        bgf[ni] = frag_read(&Bg[0][0], nq + ni * 16 + fr, kk, quad);
        bvf[ni] = frag_read(&Bv[0][0], nq + ni * 16 + fr, kk, quad);
      }
#pragma unroll
      for (int mi = 0; mi < 4; mi++)
#pragma unroll
        for (int ni = 0; ni < 2; ni++) {
          accg[mi][ni] = __builtin_amdgcn_mfma_f32_16x16x32_bf16(af[mi], bgf[ni], accg[mi][ni], 0, 0, 0);
          accv[mi][ni] = __builtin_amdgcn_mfma_f32_16x16x32_bf16(af[mi], bvf[ni], accv[mi][ni], 0, 0, 0);
        }
    }
    __syncthreads();
  }

  const int vrows = c - rb;
  const int cb = blockIdx.x * 128;
#pragma unroll
  for (int mi = 0; mi < 4; mi++) {
#pragma unroll
    for (int ni = 0; ni < 2; ni++) {
      const int col = nq + ni * 16 + fr;
      const int rowb = mq + mi * 16 + quad * 4;
#pragma unroll
      for (int r = 0; r < 4; r++) {
        const int row = rowb + r;
        if (row < vrows) {
          float g = accg[mi][ni][r];
          float v = accv[mi][ni][r];
          float s = g / (1.f + __expf(-g)) * v;  // silu(g)*v
          H[(size_t)(o + rb + row) * FF + cb + col] = f2b(s);
        }
      }
    }
  }
}

// ---------------- GEMM2: H x W2T -> scatter atomicAdd(gate*y) --------------
// 512 threads, 8 waves, wave tile M64xN32 (32 AGPR); split-K=2.
__global__ __launch_bounds__(512, 3) void gemm2_k(
    const unsigned short* __restrict__ H, const unsigned short* __restrict__ W2T,
    float* __restrict__ out, const int* __restrict__ cnt, const int* __restrict__ off,
    const int* __restrict__ slot_t, const float* __restrict__ slot_g) {
  const int e = blockIdx.z;
  const int c = cnt[e];
  const int rb = blockIdx.y * 128;
  if (rb >= c) return;
  const int o = off[e];
  const int xcol = blockIdx.x & 7;
  const int ks = blockIdx.x >> 3;          // split-K half: 0 or 1
  const unsigned short* Ab = H + (size_t)(o + rb) * FF;
  const unsigned short* Bb = W2T + ((size_t)e * 1024 + xcol * 128) * FF;

  __shared__ __align__(16) unsigned short As[128][BK];
  __shared__ __align__(16) unsigned short Bs[128][BK];

  const int tid = threadIdx.x;
  const int lane = tid & 63;
  const int w = tid >> 6;
  const int mq = (w & 1) * 64;
  const int nq = (w >> 1) * 32;
  const int fr = lane & 15;
  const int quad = lane >> 4;

  f32x4 acc[4][2];
  const f32x4 zero = {0.f, 0.f, 0.f, 0.f};
#pragma unroll
  for (int i = 0; i < 4; i++)
#pragma unroll
    for (int j = 0; j < 2; j++) acc[i][j] = zero;

  const int kbeg = ks * (FF / 2);
  for (int k0 = kbeg; k0 < kbeg + FF / 2; k0 += BK) {
    stage8(Ab, FF, k0, &As[0][0], w, lane);
    stage8(Bb, FF, k0, &Bs[0][0], w, lane);
    __syncthreads();

#pragma unroll
    for (int kk = 0; kk < 2; kk++) {
      short8 af[4], bf[2];
#pragma unroll
      for (int mi = 0; mi < 4; mi++)
        af[mi] = frag_read(&As[0][0], mq + mi * 16 + fr, kk, quad);
#pragma unroll
      for (int ni = 0; ni < 2; ni++)
        bf[ni] = frag_read(&Bs[0][0], nq + ni * 16 + fr, kk, quad);
#pragma unroll
      for (int mi = 0; mi < 4; mi++)
#pragma unroll
        for (int ni = 0; ni < 2; ni++)
          acc[mi][ni] = __builtin_amdgcn_mfma_f32_16x16x32_bf16(af[mi], bf[ni], acc[mi][ni], 0, 0, 0);
    }
    __syncthreads();
  }

  const int vrows = c - rb;
  const int cb = xcol * 128;
#pragma unroll
  for (int mi = 0; mi < 4; mi++) {
    const int rowb = mq + mi * 16 + quad * 4;
#pragma unroll
    for (int r = 0; r < 4; r++) {
      const int row = rowb + r;
      if (row < vrows) {
        const int t = slot_t[e * T_TOK + rb + row];
        const float gt = slot_g[e * T_TOK + rb + row];
        float* orow = out + (size_t)t * DIM + cb;
#pragma unroll
        for (int ni = 0; ni < 2; ni++) {
          const int col = nq + ni * 16 + fr;
          atomicAdd(orow + col, gt * acc[mi][ni][r]);
        }
      }
    }
  }
}

// ---------------------------------------------------------------------------
extern "C" void kernel_launch(void* const* d_in, const int* in_sizes, int n_in,
                              void* d_out, int out_size, void* d_ws, size_t ws_size,
                              hipStream_t stream) {
  const float* x     = (const float*)d_in[0];
  const float* rw    = (const float*)d_in[1];
  const float* w_in  = (const float*)d_in[2];
  const float* w_out = (const float*)d_in[3];
  const float* bias  = (const float*)d_in[4];
  float* out = (float*)d_out;

  char* ws = (char*)d_ws;
  int*   cnt    = (int*)ws;
  int*   off    = (int*)(ws + 32);
  int*   slot_t = (int*)(ws + 256);
  float* slot_g = (float*)(ws + 256 + 131072);
  int*   tok_e  = (int*)(ws + (512 << 10));
  float* tok_g  = (float*)(ws + (576 << 10));
  float* psum_p = (float*)(ws + (640 << 10));
  unsigned short* A1  = (unsigned short*)(ws + ((size_t)1 << 20));
  unsigned short* H   = (unsigned short*)(ws + ((size_t)18 << 20));
  unsigned short* W1T = (unsigned short*)(ws + ((size_t)51 << 20));
  unsigned short* W2T = (unsigned short*)(ws + ((size_t)116 << 20));

  init_out_k<<<16384, 256, 0, stream>>>(out, bias);                    // out = bias
  transpose_k<<<dim3(64, 16, 8), 256, 0, stream>>>(w_in, W1T, 1024, 4096);
  transpose_k<<<dim3(16, 32, 8), 256, 0, stream>>>(w_out, W2T, 2048, 1024);
  router_k<<<1024, 256, 0, stream>>>(x, rw, tok_e, tok_g, psum_p);
  bucket_k<<<1, 1024, 0, stream>>>(tok_e, tok_g, psum_p, cnt, off,
                                   slot_t, slot_g, out + (size_t)T_TOK * DIM);
  gather_k<<<dim3(8, YB, 8), 256, 0, stream>>>(x, cnt, off, slot_t, A1);
  gemm1_k<<<dim3(16, YB, 8), 512, 0, stream>>>(A1, W1T, H, cnt, off);
  gemm2_k<<<dim3(16, YB, 8), 512, 0, stream>>>(H, W2T, out, cnt, off, slot_t, slot_g);
}

// Round 6
// 468.818 us; speedup vs baseline: 1.0876x; 1.0876x over previous
//
#include <hip/hip_runtime.h>

// JetMoE FFN: B=2,S=2048 -> T=4096 tokens, D=1024, E=8, F=2048, top_k=2.
// Sparse (top-2) expert-bucketed grouped GEMM in bf16 MFMA, fp32 accum.
// R6: gemm2 atomics removed (R5 profile: 16.8M device atomics = 158G/s =
//     atomic-throughput-bound). gemm2 = pure GEMM storing f32 partials to
//     bucketed Y (aliases dead W1T); new combine_k applies gates + bias.
//     Both GEMM cores back to the R4-proven 256-thread M64N64 shape.
// ws layout (~148 MB):
//   [0..32) counts[8]  [32..64) offsets[8]
//   @256        slot_token[8][4096] int (128 KB)
//   @256+128K   tok_s int [4096][2] (32 KB)
//   @512K tok_e  @576K tok_g  @640K psum_part
//   @1MB   A1  bf16 [8192][1024] (16 MB)
//   @18MB  H   bf16 [8192][2048] (32 MB)
//   @51MB  W1T bf16 [8][4096][1024] (64 MB)  -- dead after gemm1
//   @51MB  Y   f32  [8192][1024] (32 MB)     -- aliases W1T (sequenced)
//   @116MB W2T bf16 [8][1024][2048] (32 MB)

#define T_TOK 4096
#define DIM   1024
#define NEXP  8
#define FF    2048
#define YB    16
#define BK    64

typedef __attribute__((ext_vector_type(8))) short short8;
typedef __attribute__((ext_vector_type(4))) float f32x4;

__device__ __forceinline__ unsigned short f2b(float f) {
  unsigned int u = __builtin_bit_cast(unsigned int, f);
  u += 0x7fffu + ((u >> 16) & 1u);   // round-to-nearest-even
  return (unsigned short)(u >> 16);
}

// async global->LDS, 16B per lane; lds dest = wave-uniform base + lane*16
__device__ __forceinline__ void gll16(const unsigned short* g, unsigned short* l) {
  __builtin_amdgcn_global_load_lds(
      (const __attribute__((address_space(1))) unsigned int*)g,
      (__attribute__((address_space(3))) unsigned int*)l, 16, 0, 0);
}

// Stage a 128xBK bf16 tile from 4 waves (256 threads), row-rotated chunk
// swizzle: logical 16B-chunk c of row r -> physical chunk (c+r)&7. LDS dest
// stays base+lane*16 (gll16 contiguity rule); rotation folded into the
// per-lane GLOBAL source address.
__device__ __forceinline__ void stage_tile(const unsigned short* __restrict__ gbase,
                                           size_t ldk, int k0,
                                           unsigned short* __restrict__ lds,
                                           int w, int lane) {
#pragma unroll
  for (int i = 0; i < 4; i++) {
    const int s = w * 256 + i * 64 + lane;   // physical slot, 16B units
    const int r = s >> 3;
    const int pc = s & 7;
    const int gc = ((pc - r) & 7) * 8;
    gll16(gbase + (size_t)r * ldk + k0 + gc, lds + (size_t)s * 8);
  }
}

// read MFMA fragment (8 bf16, k-contiguous) honoring the rotation swizzle
__device__ __forceinline__ short8 frag_read(const unsigned short* __restrict__ lds,
                                            int row, int kk, int quad) {
  const int p = ((kk * 4 + quad) + row) & 7;
  return __builtin_bit_cast(short8, *(const uint4*)(lds + (size_t)row * BK + p * 8));
}

// ---------------- router: fp64 logits/top-k, NO global atomics -------------
__global__ void router_k(const float* __restrict__ x, const float* __restrict__ rw,
                         int* __restrict__ tok_e, float* __restrict__ tok_g,
                         float* __restrict__ psum_part) {
  const int t = blockIdx.x * 4 + (threadIdx.x >> 6);  // one wave per token
  const int lane = threadIdx.x & 63;
  double acc[8];
#pragma unroll
  for (int e = 0; e < 8; e++) acc[e] = 0.0;
  const float* xr = x + (size_t)t * DIM;
#pragma unroll
  for (int d0 = 0; d0 < DIM; d0 += 256) {
    const int d = d0 + lane * 4;
    float4 xv = *(const float4*)(xr + d);
    const float* rwr = rw + d * 8;
#pragma unroll
    for (int j = 0; j < 4; j++) {
      double xd = (double)((j == 0) ? xv.x : (j == 1) ? xv.y : (j == 2) ? xv.z : xv.w);
#pragma unroll
      for (int e = 0; e < 8; e++) acc[e] += xd * (double)rwr[j * 8 + e];
    }
  }
#pragma unroll
  for (int off = 32; off > 0; off >>= 1) {
#pragma unroll
    for (int e = 0; e < 8; e++) acc[e] += __shfl_down(acc[e], off, 64);
  }
  __shared__ float pblk[8];
  if (threadIdx.x < 8) pblk[threadIdx.x] = 0.f;
  __syncthreads();
  if (lane == 0) {
    int i0 = -1, i1 = -1;
    double v0 = -1e300, v1 = -1e300;
#pragma unroll
    for (int e = 0; e < 8; e++) {
      double v = acc[e];
      if (v > v0) { v1 = v0; i1 = i0; v0 = v; i0 = e; }
      else if (v > v1) { v1 = v; i1 = e; }
    }
    float g1 = 1.f / (1.f + __expf((float)(v0 - v1)));  // gate of 2nd expert
    tok_e[t * 2] = i0; tok_e[t * 2 + 1] = i1;
    tok_g[t * 2] = 1.f - g1; tok_g[t * 2 + 1] = g1;
    float s = 0.f; float p[8];
#pragma unroll
    for (int e = 0; e < 8; e++) { p[e] = __expf((float)(acc[e] - v0)); s += p[e]; }
    float inv = 1.f / s;
#pragma unroll
    for (int e = 0; e < 8; e++) atomicAdd(&pblk[e], p[e] * inv);  // LDS only
  }
  __syncthreads();
  if (threadIdx.x < 8) psum_part[blockIdx.x * 8 + threadIdx.x] = pblk[threadIdx.x];
}

// ---------------- bucket: slots via ballot + LDS atomics, aux loss ---------
__global__ __launch_bounds__(1024) void bucket_k(
    const int* __restrict__ tok_e, const float* __restrict__ tok_g,
    const float* __restrict__ psum_part,
    int* __restrict__ cnt, int* __restrict__ off,
    int* __restrict__ slot_t, int* __restrict__ tok_s,
    float* __restrict__ out_aux) {
  const int tid = threadIdx.x;
  const int lane = tid & 63;
  __shared__ int lcnt[8];
  __shared__ float fsum[8];
  if (tid < 8) { lcnt[tid] = 0; fsum[tid] = 0.f; }
  __syncthreads();
#pragma unroll
  for (int rep = 0; rep < 4; rep++) {
    const int t = rep * 1024 + tid;
    const int e0 = tok_e[t * 2], e1 = tok_e[t * 2 + 1];
#pragma unroll
    for (int which = 0; which < 2; which++) {
      const int e = which ? e1 : e0;
      int slot = 0;
#pragma unroll
      for (int ex = 0; ex < 8; ex++) {
        unsigned long long m = __ballot(e == ex);
        int base = 0;
        int first = __ffsll((long long)m) - 1;
        if (m != 0ull && lane == first) base = atomicAdd(&lcnt[ex], __popcll(m));
        base = __shfl(base, first & 63, 64);
        if (e == ex) slot = base + __popcll(m & ((1ull << lane) - 1ull));
      }
      slot_t[e * T_TOK + slot] = t;
      tok_s[t * 2 + which] = slot;
    }
  }
  float p[8];
#pragma unroll
  for (int e = 0; e < 8; e++) p[e] = psum_part[tid * 8 + e];
#pragma unroll
  for (int o = 32; o > 0; o >>= 1) {
#pragma unroll
    for (int e = 0; e < 8; e++) p[e] += __shfl_down(p[e], o, 64);
  }
  if (lane == 0) {
#pragma unroll
    for (int e = 0; e < 8; e++) atomicAdd(&fsum[e], p[e]);
  }
  __syncthreads();
  if (tid == 0) {
    int o = 0; float aux = 0.f;
    for (int e = 0; e < 8; e++) {
      cnt[e] = lcnt[e]; off[e] = o; o += lcnt[e];
      aux += ((float)lcnt[e] / (4096.f * 2.f)) * (fsum[e] / 4096.f);
    }
    out_aux[0] = 8.f * aux;
  }
}

// ---------------- transpose fp32 [E][K][N] -> bf16 [E][N][K] ---------------
__global__ void transpose_k(const float* __restrict__ src, unsigned short* __restrict__ dst,
                            int K, int N) {
  __shared__ float tile[64][65];
  const int e = blockIdx.z;
  const int kb = blockIdx.y * 64, nb = blockIdx.x * 64;
  const float* s = src + (size_t)e * K * N;
  unsigned short* d = dst + (size_t)e * N * K;
  const int tid = threadIdx.x;
  const int r = tid >> 2;
  const int cseg = (tid & 3) * 16;
#pragma unroll
  for (int j = 0; j < 16; j += 4) {
    float4 v = *(const float4*)(s + (size_t)(kb + r) * N + nb + cseg + j);
    tile[r][cseg + j] = v.x; tile[r][cseg + j + 1] = v.y;
    tile[r][cseg + j + 2] = v.z; tile[r][cseg + j + 3] = v.w;
  }
  __syncthreads();
#pragma unroll
  for (int j = 0; j < 16; j += 4) {
    ushort4 o4;
    o4.x = f2b(tile[cseg + j][r]);
    o4.y = f2b(tile[cseg + j + 1][r]);
    o4.z = f2b(tile[cseg + j + 2][r]);
    o4.w = f2b(tile[cseg + j + 3][r]);
    *(ushort4*)(d + (size_t)(nb + r) * K + kb + cseg + j) = o4;
  }
}

// ---------------- gather tokens -> compact bf16 A ---------------------------
__global__ void gather_k(const float* __restrict__ x, const int* __restrict__ cnt,
                         const int* __restrict__ off, const int* __restrict__ slot_t,
                         unsigned short* __restrict__ A1) {
  const int e = blockIdx.z;
  const int rb = blockIdx.y * 128;
  const int c = cnt[e];
  if (rb >= c) return;
  const int o = off[e];
  const int cb = blockIdx.x * 128;
  for (int i = threadIdx.x; i < 128 * 32; i += 256) {  // unit = float4
    int r = i >> 5;
    int seg = cb + (i & 31) * 4;
    int row = rb + r;
    if (row >= c) continue;
    int t = slot_t[e * T_TOK + row];
    float4 v = *(const float4*)(x + (size_t)t * DIM + seg);
    ushort4 o4;
    o4.x = f2b(v.x); o4.y = f2b(v.y); o4.z = f2b(v.z); o4.w = f2b(v.w);
    *(ushort4*)(A1 + (size_t)(o + row) * DIM + seg) = o4;
  }
}

// ---------------- GEMM1: A[rows,1024] x W1T -> GLU -> H bf16 ---------------
__global__ __launch_bounds__(256, 2) void gemm1_k(
    const unsigned short* __restrict__ A1, const unsigned short* __restrict__ W1T,
    unsigned short* __restrict__ H, const int* __restrict__ cnt, const int* __restrict__ off) {
  const int e = blockIdx.z;
  const int c = cnt[e];
  const int rb = blockIdx.y * 128;
  if (rb >= c) return;
  const int o = off[e];
  const unsigned short* Ab = A1 + (size_t)(o + rb) * DIM;
  const unsigned short* Bgb = W1T + ((size_t)e * 4096 + blockIdx.x * 128) * DIM;
  const unsigned short* Bvb = Bgb + (size_t)2048 * DIM;

  __shared__ __align__(16) unsigned short As[128][BK];
  __shared__ __align__(16) unsigned short Bg[128][BK];
  __shared__ __align__(16) unsigned short Bv[128][BK];

  const int tid = threadIdx.x;
  const int lane = tid & 63;
  const int w = tid >> 6;
  const int mq = (w >> 1) * 64;
  const int nq = (w & 1) * 64;
  const int fr = lane & 15;
  const int quad = lane >> 4;

  f32x4 accg[4][4], accv[4][4];
  const f32x4 zero = {0.f, 0.f, 0.f, 0.f};
#pragma unroll
  for (int i = 0; i < 4; i++)
#pragma unroll
    for (int j = 0; j < 4; j++) { accg[i][j] = zero; accv[i][j] = zero; }

  for (int k0 = 0; k0 < DIM; k0 += BK) {
    stage_tile(Ab,  DIM, k0, &As[0][0], w, lane);
    stage_tile(Bgb, DIM, k0, &Bg[0][0], w, lane);
    stage_tile(Bvb, DIM, k0, &Bv[0][0], w, lane);
    __syncthreads();

#pragma unroll
    for (int kk = 0; kk < 2; kk++) {
      short8 af[4], bgf[4], bvf[4];
#pragma unroll
      for (int mi = 0; mi < 4; mi++)
        af[mi] = frag_read(&As[0][0], mq + mi * 16 + fr, kk, quad);
#pragma unroll
      for (int ni = 0; ni < 4; ni++) {
        bgf[ni] = frag_read(&Bg[0][0], nq + ni * 16 + fr, kk, quad);
        bvf[ni] = frag_read(&Bv[0][0], nq + ni * 16 + fr, kk, quad);
      }
#pragma unroll
      for (int mi = 0; mi < 4; mi++)
#pragma unroll
        for (int ni = 0; ni < 4; ni++) {
          accg[mi][ni] = __builtin_amdgcn_mfma_f32_16x16x32_bf16(af[mi], bgf[ni], accg[mi][ni], 0, 0, 0);
          accv[mi][ni] = __builtin_amdgcn_mfma_f32_16x16x32_bf16(af[mi], bvf[ni], accv[mi][ni], 0, 0, 0);
        }
    }
    __syncthreads();
  }

  const int vrows = c - rb;
  const int cb = blockIdx.x * 128;
#pragma unroll
  for (int mi = 0; mi < 4; mi++) {
#pragma unroll
    for (int ni = 0; ni < 4; ni++) {
      const int col = nq + ni * 16 + fr;
      const int rowb = mq + mi * 16 + quad * 4;
#pragma unroll
      for (int r = 0; r < 4; r++) {
        const int row = rowb + r;
        if (row < vrows) {
          float g = accg[mi][ni][r];
          float v = accv[mi][ni][r];
          float s = g / (1.f + __expf(-g)) * v;  // silu(g)*v
          H[(size_t)(o + rb + row) * FF + cb + col] = f2b(s);
        }
      }
    }
  }
}

// ---------------- GEMM2: H x W2T -> Y f32 (plain stores, no atomics) -------
__global__ __launch_bounds__(256, 2) void gemm2_k(
    const unsigned short* __restrict__ H, const unsigned short* __restrict__ W2T,
    float* __restrict__ Y, const int* __restrict__ cnt, const int* __restrict__ off) {
  const int e = blockIdx.z;
  const int c = cnt[e];
  const int rb = blockIdx.y * 128;
  if (rb >= c) return;
  const int o = off[e];
  const unsigned short* Ab = H + (size_t)(o + rb) * FF;
  const unsigned short* Bb = W2T + ((size_t)e * 1024 + blockIdx.x * 128) * FF;

  __shared__ __align__(16) unsigned short As[128][BK];
  __shared__ __align__(16) unsigned short Bs[128][BK];

  const int tid = threadIdx.x;
  const int lane = tid & 63;
  const int w = tid >> 6;
  const int mq = (w >> 1) * 64;
  const int nq = (w & 1) * 64;
  const int fr = lane & 15;
  const int quad = lane >> 4;

  f32x4 acc[4][4];
  const f32x4 zero = {0.f, 0.f, 0.f, 0.f};
#pragma unroll
  for (int i = 0; i < 4; i++)
#pragma unroll
    for (int j = 0; j < 4; j++) acc[i][j] = zero;

  for (int k0 = 0; k0 < FF; k0 += BK) {
    stage_tile(Ab, FF, k0, &As[0][0], w, lane);
    stage_tile(Bb, FF, k0, &Bs[0][0], w, lane);
    __syncthreads();

#pragma unroll
    for (int kk = 0; kk < 2; kk++) {
      short8 af[4], bf[4];
#pragma unroll
      for (int mi = 0; mi < 4; mi++)
        af[mi] = frag_read(&As[0][0], mq + mi * 16 + fr, kk, quad);
#pragma unroll
      for (int ni = 0; ni < 4; ni++)
        bf[ni] = frag_read(&Bs[0][0], nq + ni * 16 + fr, kk, quad);
#pragma unroll
      for (int mi = 0; mi < 4; mi++)
#pragma unroll
        for (int ni = 0; ni < 4; ni++)
          acc[mi][ni] = __builtin_amdgcn_mfma_f32_16x16x32_bf16(af[mi], bf[ni], acc[mi][ni], 0, 0, 0);
    }
    __syncthreads();
  }

  const int vrows = c - rb;
  const int cb = blockIdx.x * 128;
#pragma unroll
  for (int mi = 0; mi < 4; mi++) {
    const int rowb = mq + mi * 16 + quad * 4;
#pragma unroll
    for (int r = 0; r < 4; r++) {
      const int row = rowb + r;
      if (row < vrows) {
        float* yrow = Y + (size_t)(o + rb + row) * DIM + cb;
#pragma unroll
        for (int ni = 0; ni < 4; ni++) {
          const int col = nq + ni * 16 + fr;
          yrow[col] = acc[mi][ni][r];
        }
      }
    }
  }
}

// ---------------- combine: out = bias + g0*Y[gs0] + g1*Y[gs1] --------------
__global__ void combine_k(const float* __restrict__ Y, const int* __restrict__ tok_e,
                          const int* __restrict__ tok_s, const float* __restrict__ tok_g,
                          const int* __restrict__ off, const float* __restrict__ bias,
                          float* __restrict__ out) {
  const int t = blockIdx.x;
  const int d = threadIdx.x * 4;
  const int e0 = tok_e[t * 2], e1 = tok_e[t * 2 + 1];
  const int gs0 = off[e0] + tok_s[t * 2];
  const int gs1 = off[e1] + tok_s[t * 2 + 1];
  const float g0 = tok_g[t * 2], g1 = tok_g[t * 2 + 1];
  float4 y0 = *(const float4*)(Y + (size_t)gs0 * DIM + d);
  float4 y1 = *(const float4*)(Y + (size_t)gs1 * DIM + d);
  float4 b = *(const float4*)(bias + d);
  float4 r;
  r.x = b.x + g0 * y0.x + g1 * y1.x;
  r.y = b.y + g0 * y0.y + g1 * y1.y;
  r.z = b.z + g0 * y0.z + g1 * y1.z;
  r.w = b.w + g0 * y0.w + g1 * y1.w;
  *(float4*)(out + (size_t)t * DIM + d) = r;
}

// ---------------------------------------------------------------------------
extern "C" void kernel_launch(void* const* d_in, const int* in_sizes, int n_in,
                              void* d_out, int out_size, void* d_ws, size_t ws_size,
                              hipStream_t stream) {
  const float* x     = (const float*)d_in[0];
  const float* rw    = (const float*)d_in[1];
  const float* w_in  = (const float*)d_in[2];
  const float* w_out = (const float*)d_in[3];
  const float* bias  = (const float*)d_in[4];
  float* out = (float*)d_out;

  char* ws = (char*)d_ws;
  int*   cnt    = (int*)ws;
  int*   off    = (int*)(ws + 32);
  int*   slot_t = (int*)(ws + 256);
  int*   tok_s  = (int*)(ws + 256 + 131072);
  int*   tok_e  = (int*)(ws + (512 << 10));
  float* tok_g  = (float*)(ws + (576 << 10));
  float* psum_p = (float*)(ws + (640 << 10));
  unsigned short* A1  = (unsigned short*)(ws + ((size_t)1 << 20));
  unsigned short* H   = (unsigned short*)(ws + ((size_t)18 << 20));
  unsigned short* W1T = (unsigned short*)(ws + ((size_t)51 << 20));
  float*          Yb  = (float*)(ws + ((size_t)51 << 20));   // aliases W1T (dead)
  unsigned short* W2T = (unsigned short*)(ws + ((size_t)116 << 20));

  transpose_k<<<dim3(64, 16, 8), 256, 0, stream>>>(w_in, W1T, 1024, 4096);
  transpose_k<<<dim3(16, 32, 8), 256, 0, stream>>>(w_out, W2T, 2048, 1024);
  router_k<<<1024, 256, 0, stream>>>(x, rw, tok_e, tok_g, psum_p);
  bucket_k<<<1, 1024, 0, stream>>>(tok_e, tok_g, psum_p, cnt, off,
                                   slot_t, tok_s, out + (size_t)T_TOK * DIM);
  gather_k<<<dim3(8, YB, 8), 256, 0, stream>>>(x, cnt, off, slot_t, A1);
  gemm1_k<<<dim3(16, YB, 8), 256, 0, stream>>>(A1, W1T, H, cnt, off);
  gemm2_k<<<dim3(8, YB, 8), 256, 0, stream>>>(H, W2T, Yb, cnt, off);
  combine_k<<<T_TOK, 256, 0, stream>>>(Yb, tok_e, tok_s, tok_g, off, bias, out);
}